// Round 1
// baseline (393.066 us; speedup 1.0000x reference)
//
#include <hip/hip_runtime.h>
#include <hip/hip_bf16.h>

#define N_NODES 10000
#define N_EDGES 640000
#define CH 128

// ---------------------------------------------------------------------------
// Zero-init scratch accumulators (deg, count, cursor) — ws is poisoned 0xAA.
__global__ void init_zero_kernel(float* __restrict__ deg, int* __restrict__ cnt,
                                 int* __restrict__ cur, int n) {
    int i = blockIdx.x * blockDim.x + threadIdx.x;
    if (i < n) { deg[i] = 0.0f; cnt[i] = 0; cur[i] = 0; }
}

// ---------------------------------------------------------------------------
// Per-edge: weighted in-degree (by col) and edge count (for CSR).
__global__ void edge_count_kernel(const int* __restrict__ ei,
                                  const float* __restrict__ ew,
                                  float* __restrict__ deg, int* __restrict__ cnt) {
    int e = blockIdx.x * blockDim.x + threadIdx.x;
    if (e >= N_EDGES) return;
    int c = ei[N_EDGES + e];           // col = edge_index[1][e]
    atomicAdd(&deg[c], ew[e]);
    atomicAdd(&cnt[c], 1);
}

// dinv = rsqrt(deg + 1.0)   (+1 = self-loop weight; deg+1 > 0 always)
__global__ void dinv_kernel(const float* __restrict__ deg, float* __restrict__ dinv, int n) {
    int i = blockIdx.x * blockDim.x + threadIdx.x;
    if (i < n) dinv[i] = rsqrtf(deg[i] + 1.0f);
}

// ---------------------------------------------------------------------------
// Exclusive prefix sum of cnt[0..n) -> offs, single block of 1024.
__global__ void scan_kernel(const int* __restrict__ cnt, int* __restrict__ offs, int n) {
    __shared__ int buf[1024];
    __shared__ int carry;
    int t = threadIdx.x;
    if (t == 0) carry = 0;
    __syncthreads();
    for (int base = 0; base < n; base += 1024) {
        int i = base + t;
        int v = (i < n) ? cnt[i] : 0;
        buf[t] = v;
        __syncthreads();
        #pragma unroll
        for (int off = 1; off < 1024; off <<= 1) {
            int x = (t >= off) ? buf[t - off] : 0;
            __syncthreads();
            buf[t] += x;
            __syncthreads();
        }
        if (i < n) offs[i] = carry + buf[t] - v;   // exclusive
        __syncthreads();
        if (t == 1023) carry += buf[1023];
        __syncthreads();
    }
}

// ---------------------------------------------------------------------------
// Scatter edges into CSR order (grouped by destination col).
// edge_val = dinv[row] * w * dinv[col]  (precomputed norm, reused both layers)
__global__ void scatter_kernel(const int* __restrict__ ei, const float* __restrict__ ew,
                               const float* __restrict__ dinv,
                               const int* __restrict__ offs, int* __restrict__ cur,
                               int* __restrict__ esrc, float* __restrict__ eval) {
    int e = blockIdx.x * blockDim.x + threadIdx.x;
    if (e >= N_EDGES) return;
    int r = ei[e];
    int c = ei[N_EDGES + e];
    int p = offs[c] + atomicAdd(&cur[c], 1);
    esrc[p] = r;
    eval[p] = dinv[r] * ew[e] * dinv[c];
}

// ---------------------------------------------------------------------------
// GEMM: out[m][o] = sum_k A[m][k] * W[o][k];  A:[M][128], W:[128][128] row-major.
// 256 threads, tile 64 rows x 128 cols, per-thread microtile 8x4.
__global__ __launch_bounds__(256) void gemm128_kernel(const float* __restrict__ A,
                                                      const float* __restrict__ W,
                                                      float* __restrict__ out, int M) {
    __shared__ float As[32][68];    // [k][row], stride 68 (16B-aligned rows, broken pow2)
    __shared__ float Ws[32][132];   // [k][col]
    int tid = threadIdx.x;
    int tx = tid & 31;              // col group: 32 groups of 4
    int ty = tid >> 5;              // row group: 8 groups of 8
    int row0 = blockIdx.x * 64;
    float acc[8][4] = {};
    for (int k0 = 0; k0 < 128; k0 += 32) {
        #pragma unroll
        for (int i = 0; i < 8; ++i) {          // A chunk: 64x32
            int idx = tid + i * 256;
            int r = idx >> 5, k = idx & 31;
            int gr = row0 + r;
            As[k][r] = (gr < M) ? A[gr * CH + k0 + k] : 0.0f;
        }
        #pragma unroll
        for (int i = 0; i < 16; ++i) {         // W chunk: 128x32
            int idx = tid + i * 256;
            int o = idx >> 5, k = idx & 31;
            Ws[k][o] = W[o * CH + k0 + k];
        }
        __syncthreads();
        #pragma unroll
        for (int kk = 0; kk < 32; ++kk) {
            float a[8], w[4];
            #pragma unroll
            for (int j = 0; j < 8; ++j) a[j] = As[kk][ty * 8 + j];
            #pragma unroll
            for (int c = 0; c < 4; ++c) w[c] = Ws[kk][tx * 4 + c];
            #pragma unroll
            for (int j = 0; j < 8; ++j)
                #pragma unroll
                for (int c = 0; c < 4; ++c)
                    acc[j][c] += a[j] * w[c];
        }
        __syncthreads();
    }
    #pragma unroll
    for (int j = 0; j < 8; ++j) {
        int gr = row0 + ty * 8 + j;
        if (gr < M) {
            float4 v = make_float4(acc[j][0], acc[j][1], acc[j][2], acc[j][3]);
            *reinterpret_cast<float4*>(&out[gr * CH + tx * 4]) = v;
        }
    }
}

// ---------------------------------------------------------------------------
// Aggregation: out[n][t] = relu( bias[t] + dinv[n]^2 * xw[n][t]
//                                + sum_{e in CSR[n]} eval[e] * xw[esrc[e]][t] )
// One block (128 threads = channels) per destination node. Atomic-free.
__global__ __launch_bounds__(128) void agg_kernel(const float* __restrict__ xw,
        const int* __restrict__ esrc, const float* __restrict__ eval,
        const int* __restrict__ offs, const int* __restrict__ cnt,
        const float* __restrict__ dinv, const float* __restrict__ bias,
        float* __restrict__ out) {
    int n = blockIdx.x;
    int t = threadIdx.x;
    float d = dinv[n];
    float acc = d * d * xw[n * CH + t];
    int start = offs[n];
    int num = cnt[n];
    for (int i = 0; i < num; ++i) {
        int s = esrc[start + i];
        float v = eval[start + i];
        acc += v * xw[s * CH + t];
    }
    acc += bias[t];
    out[n * CH + t] = fmaxf(acc, 0.0f);
}

// ---------------------------------------------------------------------------
// conv1d(k=3) + FC are both linear -> fold into v[i][k] (384) and scalar c0.
// conv_w layout: [o][i][k] row-major = o*384 + i*3 + k
__global__ void prep_convfc_kernel(const float* __restrict__ conv_w,
                                   const float* __restrict__ conv_b,
                                   const float* __restrict__ fc_w,
                                   const float* __restrict__ fc_b,
                                   float* __restrict__ v, float* __restrict__ c0) {
    int t = blockIdx.x * blockDim.x + threadIdx.x;
    if (t < 384) {
        float s = 0.0f;
        for (int o = 0; o < CH; ++o) s += fc_w[o] * conv_w[o * 384 + t];
        v[t] = s;
    } else if (t == 384) {
        float s = fc_b[0];
        for (int o = 0; o < CH; ++o) s += fc_w[o] * conv_b[o];
        *c0 = s;
    }
}

// out[n] = c0 + sum_k sum_i h[n+k-1][i] * v[i*3+k]   (zero-pad at boundaries)
// One block (128 threads = channels) per node; block reduction.
__global__ __launch_bounds__(128) void convfc_kernel(const float* __restrict__ h,
        const float* __restrict__ v, const float* __restrict__ c0,
        float* __restrict__ out, int N) {
    int n = blockIdx.x;
    int t = threadIdx.x;
    float p = 0.0f;
    if (n > 0)     p += h[(n - 1) * CH + t] * v[t * 3 + 0];
    p += h[n * CH + t] * v[t * 3 + 1];
    if (n < N - 1) p += h[(n + 1) * CH + t] * v[t * 3 + 2];
    #pragma unroll
    for (int off = 32; off > 0; off >>= 1) p += __shfl_down(p, off, 64);
    __shared__ float red[2];
    if ((t & 63) == 0) red[t >> 6] = p;
    __syncthreads();
    if (t == 0) out[n] = red[0] + red[1] + *c0;
}

// ---------------------------------------------------------------------------
extern "C" void kernel_launch(void* const* d_in, const int* in_sizes, int n_in,
                              void* d_out, int out_size, void* d_ws, size_t ws_size,
                              hipStream_t stream) {
    const float* x       = (const float*)d_in[0];   // [10000,128]
    const int*   ei      = (const int*)d_in[1];     // [2,640000] (int32 per harness)
    const float* ew      = (const float*)d_in[2];   // [640000]
    const float* W1      = (const float*)d_in[3];   // [128,128]
    const float* b1      = (const float*)d_in[4];
    const float* W2      = (const float*)d_in[5];
    const float* b2      = (const float*)d_in[6];
    const float* conv_w  = (const float*)d_in[7];   // [128,128,3]
    const float* conv_b  = (const float*)d_in[8];
    const float* fc_w    = (const float*)d_in[9];   // [1,128]
    const float* fc_b    = (const float*)d_in[10];
    float* out = (float*)d_out;                     // [10000]

    // Workspace layout (floats/ints, 4B units)
    float* bufA   = (float*)d_ws;                   // 10000*128
    float* bufB   = bufA + N_NODES * CH;            // 10000*128
    int*   esrc   = (int*)(bufB + N_NODES * CH);    // 640000
    float* eval   = (float*)(esrc + N_EDGES);       // 640000
    float* deg    = eval + N_EDGES;                 // 10000
    float* dinv   = deg + N_NODES;                  // 10000
    int*   cnt    = (int*)(dinv + N_NODES);         // 10000
    int*   offs   = cnt + N_NODES;                  // 10000
    int*   cursor = offs + N_NODES;                 // 10000
    float* vbuf   = (float*)(cursor + N_NODES);     // 384
    float* c0     = vbuf + 384;                     // 1

    // --- CSR build + normalization (once per call) ---
    init_zero_kernel<<<(N_NODES + 255) / 256, 256, 0, stream>>>(deg, cnt, cursor, N_NODES);
    edge_count_kernel<<<(N_EDGES + 255) / 256, 256, 0, stream>>>(ei, ew, deg, cnt);
    dinv_kernel<<<(N_NODES + 255) / 256, 256, 0, stream>>>(deg, dinv, N_NODES);
    scan_kernel<<<1, 1024, 0, stream>>>(cnt, offs, N_NODES);
    scatter_kernel<<<(N_EDGES + 255) / 256, 256, 0, stream>>>(ei, ew, dinv, offs, cursor, esrc, eval);

    // --- conv+fc weight folding (independent, cheap) ---
    prep_convfc_kernel<<<1, 512, 0, stream>>>(conv_w, conv_b, fc_w, fc_b, vbuf, c0);

    const int gemm_grid = (N_NODES + 63) / 64;
    // --- layer 1: xw1 = x @ W1^T ; h1 = relu(agg(xw1) + b1) ---
    gemm128_kernel<<<gemm_grid, 256, 0, stream>>>(x, W1, bufA, N_NODES);
    agg_kernel<<<N_NODES, 128, 0, stream>>>(bufA, esrc, eval, offs, cnt, dinv, b1, bufB);

    // --- layer 2: xw2 = h1 @ W2^T ; h2 = relu(agg(xw2) + b2) ---
    gemm128_kernel<<<gemm_grid, 256, 0, stream>>>(bufB, W2, bufA, N_NODES);
    agg_kernel<<<N_NODES, 128, 0, stream>>>(bufA, esrc, eval, offs, cnt, dinv, b2, bufB);

    // --- fused temporal conv + fc ---
    convfc_kernel<<<N_NODES, 128, 0, stream>>>(bufB, vbuf, c0, out, N_NODES);
}

// Round 2
// 351.541 us; speedup vs baseline: 1.1181x; 1.1181x over previous
//
#include <hip/hip_runtime.h>
#include <hip/hip_bf16.h>

#define N_NODES 10000
#define N_EDGES 640000
#define CH 128
#define NB 64            // histogram blocks
#define EPB (N_EDGES / NB)   // 10000 edges per block

// ---------------------------------------------------------------------------
// Phase A: per-block LDS histograms (counts + weighted degree), no global atomics.
// Two sequential passes reuse the same 40KB LDS array.
__global__ __launch_bounds__(256) void hist_kernel(const int* __restrict__ ei,
                                                   const float* __restrict__ ew,
                                                   int* __restrict__ hist,
                                                   float* __restrict__ dhist) {
    __shared__ int h[N_NODES];                 // 40 KB
    float* hf = (float*)h;
    int b = blockIdx.x, t = threadIdx.x;
    int e0 = b * EPB;
    // pass 1: counts
    for (int i = t; i < N_NODES; i += 256) h[i] = 0;
    __syncthreads();
    for (int i = t; i < EPB; i += 256) {
        int c = ei[N_EDGES + e0 + i];
        atomicAdd(&h[c], 1);                   // LDS atomic
    }
    __syncthreads();
    for (int i = t; i < N_NODES; i += 256) hist[b * N_NODES + i] = h[i];
    __syncthreads();
    // pass 2: weighted degree
    for (int i = t; i < N_NODES; i += 256) hf[i] = 0.0f;
    __syncthreads();
    for (int i = t; i < EPB; i += 256) {
        int c = ei[N_EDGES + e0 + i];
        atomicAdd(&hf[c], ew[e0 + i]);         // LDS float atomic
    }
    __syncthreads();
    for (int i = t; i < N_NODES; i += 256) dhist[b * N_NODES + i] = hf[i];
}

// ---------------------------------------------------------------------------
// Phase B: reduce histograms across blocks -> tot (cnt) and dinv.
__global__ void reduce_kernel(const int* __restrict__ hist, const float* __restrict__ dhist,
                              int* __restrict__ tot, float* __restrict__ dinv) {
    int n = blockIdx.x * blockDim.x + threadIdx.x;
    if (n >= N_NODES) return;
    int c = 0; float d = 0.0f;
    #pragma unroll 4
    for (int b = 0; b < NB; ++b) {
        c += hist[b * N_NODES + n];
        d += dhist[b * N_NODES + n];
    }
    tot[n] = c;
    dinv[n] = rsqrtf(d + 1.0f);                // +1 = self-loop weight
}

// ---------------------------------------------------------------------------
// Exclusive prefix sum of tot -> offs. Single block, shuffle-based (few barriers).
__global__ __launch_bounds__(1024) void scan_kernel(const int* __restrict__ tot,
                                                    int* __restrict__ offs, int n) {
    __shared__ int wsum[16];
    __shared__ int carry_s;
    int t = threadIdx.x;
    int lane = t & 63, wave = t >> 6;
    if (t == 0) carry_s = 0;
    __syncthreads();
    for (int base = 0; base < n; base += 1024) {
        int i = base + t;
        int v = (i < n) ? tot[i] : 0;
        int s = v;
        #pragma unroll
        for (int off = 1; off < 64; off <<= 1) {
            int u = __shfl_up(s, off, 64);
            if (lane >= off) s += u;
        }
        if (lane == 63) wsum[wave] = s;
        __syncthreads();
        if (wave == 0) {
            int ws = (lane < 16) ? wsum[lane] : 0;
            #pragma unroll
            for (int off = 1; off < 16; off <<= 1) {
                int u = __shfl_up(ws, off, 64);
                if (lane >= off) ws += u;
            }
            if (lane < 16) wsum[lane] = ws;    // inclusive wave sums
        }
        __syncthreads();
        int waveoff = (wave > 0) ? wsum[wave - 1] : 0;
        int incl = s + waveoff + carry_s;
        if (i < n) offs[i] = incl - v;         // exclusive
        __syncthreads();                       // everyone done reading carry_s
        if (t == 1023) carry_s = incl;
        __syncthreads();
    }
}

// ---------------------------------------------------------------------------
// Phase C: convert hist in-place into per-(block,node) start cursors:
// bofs[b][n] = offs[n] + sum_{b'<b} hist[b'][n]
__global__ void bofs_kernel(int* __restrict__ hist, const int* __restrict__ offs) {
    int n = blockIdx.x * blockDim.x + threadIdx.x;
    if (n >= N_NODES) return;
    int run = offs[n];
    for (int b = 0; b < NB; ++b) {
        int h = hist[b * N_NODES + n];
        hist[b * N_NODES + n] = run;
        run += h;
    }
}

// ---------------------------------------------------------------------------
// Phase D: scatter edges into CSR order using LDS cursors (no global atomics).
__global__ __launch_bounds__(256) void scatter_kernel(const int* __restrict__ ei,
        const float* __restrict__ ew, const float* __restrict__ dinv,
        const int* __restrict__ bofs, int* __restrict__ esrc, float* __restrict__ eval) {
    __shared__ int cur[N_NODES];               // 40 KB
    int b = blockIdx.x, t = threadIdx.x;
    for (int i = t; i < N_NODES; i += 256) cur[i] = bofs[b * N_NODES + i];
    __syncthreads();
    int e0 = b * EPB;
    for (int i = t; i < EPB; i += 256) {
        int e = e0 + i;
        int r = ei[e];
        int c = ei[N_EDGES + e];
        int p = atomicAdd(&cur[c], 1);         // LDS atomic
        esrc[p] = r;
        eval[p] = dinv[r] * ew[e] * dinv[c];
    }
}

// ---------------------------------------------------------------------------
// GEMM: out[m][o] = sum_k A[m][k] * W[o][k];  A:[M][128], W:[128][128] row-major.
__global__ __launch_bounds__(256) void gemm128_kernel(const float* __restrict__ A,
                                                      const float* __restrict__ W,
                                                      float* __restrict__ out, int M) {
    __shared__ float As[32][68];
    __shared__ float Ws[32][132];
    int tid = threadIdx.x;
    int tx = tid & 31;
    int ty = tid >> 5;
    int row0 = blockIdx.x * 64;
    float acc[8][4] = {};
    for (int k0 = 0; k0 < 128; k0 += 32) {
        #pragma unroll
        for (int i = 0; i < 8; ++i) {
            int idx = tid + i * 256;
            int r = idx >> 5, k = idx & 31;
            int gr = row0 + r;
            As[k][r] = (gr < M) ? A[gr * CH + k0 + k] : 0.0f;
        }
        #pragma unroll
        for (int i = 0; i < 16; ++i) {
            int idx = tid + i * 256;
            int o = idx >> 5, k = idx & 31;
            Ws[k][o] = W[o * CH + k0 + k];
        }
        __syncthreads();
        #pragma unroll
        for (int kk = 0; kk < 32; ++kk) {
            float a[8], w[4];
            #pragma unroll
            for (int j = 0; j < 8; ++j) a[j] = As[kk][ty * 8 + j];
            #pragma unroll
            for (int c = 0; c < 4; ++c) w[c] = Ws[kk][tx * 4 + c];
            #pragma unroll
            for (int j = 0; j < 8; ++j)
                #pragma unroll
                for (int c = 0; c < 4; ++c)
                    acc[j][c] += a[j] * w[c];
        }
        __syncthreads();
    }
    #pragma unroll
    for (int j = 0; j < 8; ++j) {
        int gr = row0 + ty * 8 + j;
        if (gr < M) {
            float4 v = make_float4(acc[j][0], acc[j][1], acc[j][2], acc[j][3]);
            *reinterpret_cast<float4*>(&out[gr * CH + tx * 4]) = v;
        }
    }
}

// ---------------------------------------------------------------------------
// Aggregation: out[n][t] = relu( bias[t] + dinv[n]^2 * xw[n][t]
//                                + sum_{e in CSR[n]} eval[e] * xw[esrc[e]][t] )
__global__ __launch_bounds__(128) void agg_kernel(const float* __restrict__ xw,
        const int* __restrict__ esrc, const float* __restrict__ eval,
        const int* __restrict__ offs, const int* __restrict__ cnt,
        const float* __restrict__ dinv, const float* __restrict__ bias,
        float* __restrict__ out) {
    int n = blockIdx.x;
    int t = threadIdx.x;
    float d = dinv[n];
    float acc = d * d * xw[n * CH + t];
    int start = offs[n];
    int num = cnt[n];
    for (int i = 0; i < num; ++i) {
        int s = esrc[start + i];
        float v = eval[start + i];
        acc += v * xw[s * CH + t];
    }
    acc += bias[t];
    out[n * CH + t] = fmaxf(acc, 0.0f);
}

// ---------------------------------------------------------------------------
// conv1d(k=3) + FC folded: v[i][k] = sum_o fc_w[o]*conv_w[o][i][k]; c0 scalar.
__global__ void prep_convfc_kernel(const float* __restrict__ conv_w,
                                   const float* __restrict__ conv_b,
                                   const float* __restrict__ fc_w,
                                   const float* __restrict__ fc_b,
                                   float* __restrict__ v, float* __restrict__ c0) {
    int t = blockIdx.x * blockDim.x + threadIdx.x;
    if (t < 384) {
        float s = 0.0f;
        for (int o = 0; o < CH; ++o) s += fc_w[o] * conv_w[o * 384 + t];
        v[t] = s;
    } else if (t == 384) {
        float s = fc_b[0];
        for (int o = 0; o < CH; ++o) s += fc_w[o] * conv_b[o];
        *c0 = s;
    }
}

__global__ __launch_bounds__(128) void convfc_kernel(const float* __restrict__ h,
        const float* __restrict__ v, const float* __restrict__ c0,
        float* __restrict__ out, int N) {
    int n = blockIdx.x;
    int t = threadIdx.x;
    float p = 0.0f;
    if (n > 0)     p += h[(n - 1) * CH + t] * v[t * 3 + 0];
    p += h[n * CH + t] * v[t * 3 + 1];
    if (n < N - 1) p += h[(n + 1) * CH + t] * v[t * 3 + 2];
    #pragma unroll
    for (int off = 32; off > 0; off >>= 1) p += __shfl_down(p, off, 64);
    __shared__ float red[2];
    if ((t & 63) == 0) red[t >> 6] = p;
    __syncthreads();
    if (t == 0) out[n] = red[0] + red[1] + *c0;
}

// ---------------------------------------------------------------------------
extern "C" void kernel_launch(void* const* d_in, const int* in_sizes, int n_in,
                              void* d_out, int out_size, void* d_ws, size_t ws_size,
                              hipStream_t stream) {
    const float* x       = (const float*)d_in[0];
    const int*   ei      = (const int*)d_in[1];
    const float* ew      = (const float*)d_in[2];
    const float* W1      = (const float*)d_in[3];
    const float* b1      = (const float*)d_in[4];
    const float* W2      = (const float*)d_in[5];
    const float* b2      = (const float*)d_in[6];
    const float* conv_w  = (const float*)d_in[7];
    const float* conv_b  = (const float*)d_in[8];
    const float* fc_w    = (const float*)d_in[9];
    const float* fc_b    = (const float*)d_in[10];
    float* out = (float*)d_out;

    // Workspace layout. NOTE: eval aliases dhist (dhist dead after reduce_kernel,
    // eval written only in scatter_kernel which runs later — stream-ordered).
    float* bufA   = (float*)d_ws;                   // 1,280,000 f
    float* bufB   = bufA + N_NODES * CH;            // 1,280,000 f
    int*   esrc   = (int*)(bufB + N_NODES * CH);    // 640,000 i
    float* eval   = (float*)(esrc + N_EDGES);       // 640,000 f  (== dhist)
    float* dhist  = eval;                           //   alias
    int*   hist   = (int*)(eval + N_EDGES);         // 640,000 i  (becomes bofs in-place)
    int*   tot    = hist + N_EDGES;                 // 10,000 i
    int*   offs   = tot + N_NODES;                  // 10,000 i
    float* dinv   = (float*)(offs + N_NODES);       // 10,000 f
    float* vbuf   = dinv + N_NODES;                 // 384 f
    float* c0     = vbuf + 384;                     // 1 f

    // --- CSR build, atomic-free at global scope ---
    hist_kernel<<<NB, 256, 0, stream>>>(ei, ew, hist, dhist);
    reduce_kernel<<<(N_NODES + 255) / 256, 256, 0, stream>>>(hist, dhist, tot, dinv);
    scan_kernel<<<1, 1024, 0, stream>>>(tot, offs, N_NODES);
    bofs_kernel<<<(N_NODES + 255) / 256, 256, 0, stream>>>(hist, offs);
    scatter_kernel<<<NB, 256, 0, stream>>>(ei, ew, dinv, hist, esrc, eval);

    // --- conv+fc weight folding ---
    prep_convfc_kernel<<<1, 512, 0, stream>>>(conv_w, conv_b, fc_w, fc_b, vbuf, c0);

    const int gemm_grid = (N_NODES + 63) / 64;
    // --- layer 1 ---
    gemm128_kernel<<<gemm_grid, 256, 0, stream>>>(x, W1, bufA, N_NODES);
    agg_kernel<<<N_NODES, 128, 0, stream>>>(bufA, esrc, eval, offs, tot, dinv, b1, bufB);
    // --- layer 2 ---
    gemm128_kernel<<<gemm_grid, 256, 0, stream>>>(bufB, W2, bufA, N_NODES);
    agg_kernel<<<N_NODES, 128, 0, stream>>>(bufA, esrc, eval, offs, tot, dinv, b2, bufB);
    // --- fused temporal conv + fc ---
    convfc_kernel<<<N_NODES, 128, 0, stream>>>(bufB, vbuf, c0, out, N_NODES);
}

// Round 3
// 250.833 us; speedup vs baseline: 1.5670x; 1.4015x over previous
//
#include <hip/hip_runtime.h>
#include <hip/hip_bf16.h>

#define N_NODES 10000
#define N_EDGES 640000
#define CH 128
#define NB 128               // histogram/scatter blocks
#define EPB (N_EDGES / NB)   // 5000 edges per block

// ---------------------------------------------------------------------------
// Phase A: per-block LDS histograms (counts + weighted degree), no global atomics.
// Two sequential passes reuse the same 40KB LDS array.
__global__ __launch_bounds__(256) void hist_kernel(const int* __restrict__ ei,
                                                   const float* __restrict__ ew,
                                                   int* __restrict__ hist,
                                                   float* __restrict__ dhist) {
    __shared__ int h[N_NODES];                 // 40 KB
    float* hf = (float*)h;
    int b = blockIdx.x, t = threadIdx.x;
    int e0 = b * EPB;
    // pass 1: counts
    for (int i = t; i < N_NODES; i += 256) h[i] = 0;
    __syncthreads();
    for (int i = t; i < EPB; i += 256) {
        int c = ei[N_EDGES + e0 + i];
        atomicAdd(&h[c], 1);                   // LDS atomic
    }
    __syncthreads();
    for (int i = t; i < N_NODES; i += 256) hist[b * N_NODES + i] = h[i];
    __syncthreads();
    // pass 2: weighted degree
    for (int i = t; i < N_NODES; i += 256) hf[i] = 0.0f;
    __syncthreads();
    for (int i = t; i < EPB; i += 256) {
        int c = ei[N_EDGES + e0 + i];
        atomicAdd(&hf[c], ew[e0 + i]);         // LDS float atomic
    }
    __syncthreads();
    for (int i = t; i < N_NODES; i += 256) dhist[b * N_NODES + i] = hf[i];
}

// ---------------------------------------------------------------------------
// Phase B: reduce histograms across blocks -> tot (cnt) and dinv.
__global__ void reduce_kernel(const int* __restrict__ hist, const float* __restrict__ dhist,
                              int* __restrict__ tot, float* __restrict__ dinv) {
    int n = blockIdx.x * blockDim.x + threadIdx.x;
    if (n >= N_NODES) return;
    int c = 0; float d = 0.0f;
    #pragma unroll 4
    for (int b = 0; b < NB; ++b) {
        c += hist[b * N_NODES + n];
        d += dhist[b * N_NODES + n];
    }
    tot[n] = c;
    dinv[n] = rsqrtf(d + 1.0f);                // +1 = self-loop weight
}

// ---------------------------------------------------------------------------
// Exclusive prefix sum of tot -> offs. Single block, shuffle-based.
__global__ __launch_bounds__(1024) void scan_kernel(const int* __restrict__ tot,
                                                    int* __restrict__ offs, int n) {
    __shared__ int wsum[16];
    __shared__ int carry_s;
    int t = threadIdx.x;
    int lane = t & 63, wave = t >> 6;
    if (t == 0) carry_s = 0;
    __syncthreads();
    for (int base = 0; base < n; base += 1024) {
        int i = base + t;
        int v = (i < n) ? tot[i] : 0;
        int s = v;
        #pragma unroll
        for (int off = 1; off < 64; off <<= 1) {
            int u = __shfl_up(s, off, 64);
            if (lane >= off) s += u;
        }
        if (lane == 63) wsum[wave] = s;
        __syncthreads();
        if (wave == 0) {
            int ws = (lane < 16) ? wsum[lane] : 0;
            #pragma unroll
            for (int off = 1; off < 16; off <<= 1) {
                int u = __shfl_up(ws, off, 64);
                if (lane >= off) ws += u;
            }
            if (lane < 16) wsum[lane] = ws;    // inclusive wave sums
        }
        __syncthreads();
        int waveoff = (wave > 0) ? wsum[wave - 1] : 0;
        int incl = s + waveoff + carry_s;
        if (i < n) offs[i] = incl - v;         // exclusive
        __syncthreads();
        if (t == 1023) carry_s = incl;
        __syncthreads();
    }
}

// ---------------------------------------------------------------------------
// Phase C: hist -> per-(block,node) start cursors (in-place).
__global__ void bofs_kernel(int* __restrict__ hist, const int* __restrict__ offs) {
    int n = blockIdx.x * blockDim.x + threadIdx.x;
    if (n >= N_NODES) return;
    int run = offs[n];
    for (int b = 0; b < NB; ++b) {
        int h = hist[b * N_NODES + n];
        hist[b * N_NODES + n] = run;
        run += h;
    }
}

// ---------------------------------------------------------------------------
// Phase D: scatter edges into CSR order; packed {src, val} 8B records.
__global__ __launch_bounds__(256) void scatter_kernel(const int* __restrict__ ei,
        const float* __restrict__ ew, const float* __restrict__ dinv,
        const int* __restrict__ bofs, int2* __restrict__ erec) {
    __shared__ int cur[N_NODES];               // 40 KB
    int b = blockIdx.x, t = threadIdx.x;
    for (int i = t; i < N_NODES; i += 256) cur[i] = bofs[b * N_NODES + i];
    __syncthreads();
    int e0 = b * EPB;
    for (int i = t; i < EPB; i += 256) {
        int e = e0 + i;
        int r = ei[e];
        int c = ei[N_EDGES + e];
        int p = atomicAdd(&cur[c], 1);         // LDS atomic
        float v = dinv[r] * ew[e] * dinv[c];
        erec[p] = make_int2(r, __float_as_int(v));
    }
}

// ---------------------------------------------------------------------------
// GEMM: out[m][o] = sum_k A[m][k] * W[o][k];  A:[M][128], W:[128][128] row-major.
__global__ __launch_bounds__(256) void gemm128_kernel(const float* __restrict__ A,
                                                      const float* __restrict__ W,
                                                      float* __restrict__ out, int M) {
    __shared__ float As[32][68];
    __shared__ float Ws[32][132];
    int tid = threadIdx.x;
    int tx = tid & 31;
    int ty = tid >> 5;
    int row0 = blockIdx.x * 64;
    float acc[8][4] = {};
    for (int k0 = 0; k0 < 128; k0 += 32) {
        #pragma unroll
        for (int i = 0; i < 8; ++i) {
            int idx = tid + i * 256;
            int r = idx >> 5, k = idx & 31;
            int gr = row0 + r;
            As[k][r] = (gr < M) ? A[gr * CH + k0 + k] : 0.0f;
        }
        #pragma unroll
        for (int i = 0; i < 16; ++i) {
            int idx = tid + i * 256;
            int o = idx >> 5, k = idx & 31;
            Ws[k][o] = W[o * CH + k0 + k];
        }
        __syncthreads();
        #pragma unroll
        for (int kk = 0; kk < 32; ++kk) {
            float a[8], w[4];
            #pragma unroll
            for (int j = 0; j < 8; ++j) a[j] = As[kk][ty * 8 + j];
            #pragma unroll
            for (int c = 0; c < 4; ++c) w[c] = Ws[kk][tx * 4 + c];
            #pragma unroll
            for (int j = 0; j < 8; ++j)
                #pragma unroll
                for (int c = 0; c < 4; ++c)
                    acc[j][c] += a[j] * w[c];
        }
        __syncthreads();
    }
    #pragma unroll
    for (int j = 0; j < 8; ++j) {
        int gr = row0 + ty * 8 + j;
        if (gr < M) {
            float4 v = make_float4(acc[j][0], acc[j][1], acc[j][2], acc[j][3]);
            *reinterpret_cast<float4*>(&out[gr * CH + tx * 4]) = v;
        }
    }
}

// ---------------------------------------------------------------------------
// Aggregation, MLP-optimized: 32 lanes per node (float4/lane), 8 nodes/block,
// edge loop unrolled x8 -> 8 independent dwordx4 gathers in flight per group.
__global__ __launch_bounds__(256) void agg_kernel(const float4* __restrict__ xw4,
        const int2* __restrict__ erec, const int* __restrict__ offs,
        const int* __restrict__ cnt, const float* __restrict__ dinv,
        const float4* __restrict__ bias4, float4* __restrict__ out4) {
    int l = threadIdx.x & 31;                  // channel quad
    int g = threadIdx.x >> 5;                  // node group 0..7
    int n = blockIdx.x * 8 + g;                // grid = 1250 -> n < 10000 always
    float d = dinv[n];
    float dd = d * d;
    float4 self = xw4[n * 32 + l];
    float4 acc = make_float4(dd * self.x, dd * self.y, dd * self.z, dd * self.w);
    int start = offs[n];
    int num = cnt[n];
    int i = 0;
    for (; i + 8 <= num; i += 8) {
        int2 r[8];
        #pragma unroll
        for (int j = 0; j < 8; ++j) r[j] = erec[start + i + j];
        float4 f[8];
        #pragma unroll
        for (int j = 0; j < 8; ++j) f[j] = xw4[r[j].x * 32 + l];
        #pragma unroll
        for (int j = 0; j < 8; ++j) {
            float v = __int_as_float(r[j].y);
            acc.x += v * f[j].x; acc.y += v * f[j].y;
            acc.z += v * f[j].z; acc.w += v * f[j].w;
        }
    }
    for (; i < num; ++i) {
        int2 r = erec[start + i];
        float4 f = xw4[r.x * 32 + l];
        float v = __int_as_float(r.y);
        acc.x += v * f.x; acc.y += v * f.y; acc.z += v * f.z; acc.w += v * f.w;
    }
    float4 bb = bias4[l];
    acc.x = fmaxf(acc.x + bb.x, 0.0f);
    acc.y = fmaxf(acc.y + bb.y, 0.0f);
    acc.z = fmaxf(acc.z + bb.z, 0.0f);
    acc.w = fmaxf(acc.w + bb.w, 0.0f);
    out4[n * 32 + l] = acc;
}

// ---------------------------------------------------------------------------
// conv1d(k=3) + FC folded: v[i][k] = sum_o fc_w[o]*conv_w[o][i][k]; c0 scalar.
__global__ void prep_convfc_kernel(const float* __restrict__ conv_w,
                                   const float* __restrict__ conv_b,
                                   const float* __restrict__ fc_w,
                                   const float* __restrict__ fc_b,
                                   float* __restrict__ v, float* __restrict__ c0) {
    int t = blockIdx.x * blockDim.x + threadIdx.x;
    if (t < 384) {
        float s = 0.0f;
        for (int o = 0; o < CH; ++o) s += fc_w[o] * conv_w[o * 384 + t];
        v[t] = s;
    } else if (t == 384) {
        float s = fc_b[0];
        for (int o = 0; o < CH; ++o) s += fc_w[o] * conv_b[o];
        *c0 = s;
    }
}

__global__ __launch_bounds__(128) void convfc_kernel(const float* __restrict__ h,
        const float* __restrict__ v, const float* __restrict__ c0,
        float* __restrict__ out, int N) {
    int n = blockIdx.x;
    int t = threadIdx.x;
    float p = 0.0f;
    if (n > 0)     p += h[(n - 1) * CH + t] * v[t * 3 + 0];
    p += h[n * CH + t] * v[t * 3 + 1];
    if (n < N - 1) p += h[(n + 1) * CH + t] * v[t * 3 + 2];
    #pragma unroll
    for (int off = 32; off > 0; off >>= 1) p += __shfl_down(p, off, 64);
    __shared__ float red[2];
    if ((t & 63) == 0) red[t >> 6] = p;
    __syncthreads();
    if (t == 0) out[n] = red[0] + red[1] + *c0;
}

// ---------------------------------------------------------------------------
extern "C" void kernel_launch(void* const* d_in, const int* in_sizes, int n_in,
                              void* d_out, int out_size, void* d_ws, size_t ws_size,
                              hipStream_t stream) {
    const float* x       = (const float*)d_in[0];
    const int*   ei      = (const int*)d_in[1];
    const float* ew      = (const float*)d_in[2];
    const float* W1      = (const float*)d_in[3];
    const float* b1      = (const float*)d_in[4];
    const float* W2      = (const float*)d_in[5];
    const float* b2      = (const float*)d_in[6];
    const float* conv_w  = (const float*)d_in[7];
    const float* conv_b  = (const float*)d_in[8];
    const float* fc_w    = (const float*)d_in[9];
    const float* fc_b    = (const float*)d_in[10];
    float* out = (float*)d_out;

    // Workspace layout with stream-ordered aliasing:
    //   hist  (NB*10000 i = 1.28M) aliases bufA  (dead after scatter; bufA first
    //                                             written by gemm1, later in stream)
    //   dhist (NB*10000 f = 1.28M) aliases erec  (dead after reduce; erec first
    //                                             written by scatter, later in stream)
    float* bufA   = (float*)d_ws;                   // 1,280,000 f
    float* bufB   = bufA + N_NODES * CH;            // 1,280,000 f
    int2*  erec   = (int2*)(bufB + N_NODES * CH);   // 640,000 x 8B
    int*   hist   = (int*)bufA;                     // alias
    float* dhist  = (float*)erec;                   // alias
    int*   tot    = (int*)(erec + N_EDGES);         // 10,000 i
    int*   offs   = tot + N_NODES;                  // 10,000 i
    float* dinv   = (float*)(offs + N_NODES);       // 10,000 f
    float* vbuf   = dinv + N_NODES;                 // 384 f
    float* c0     = vbuf + 384;                     // 1 f

    // --- CSR build, atomic-free at global scope ---
    hist_kernel<<<NB, 256, 0, stream>>>(ei, ew, hist, dhist);
    reduce_kernel<<<(N_NODES + 255) / 256, 256, 0, stream>>>(hist, dhist, tot, dinv);
    scan_kernel<<<1, 1024, 0, stream>>>(tot, offs, N_NODES);
    bofs_kernel<<<(N_NODES + 255) / 256, 256, 0, stream>>>(hist, offs);
    scatter_kernel<<<NB, 256, 0, stream>>>(ei, ew, dinv, hist, erec);

    // --- conv+fc weight folding ---
    prep_convfc_kernel<<<1, 512, 0, stream>>>(conv_w, conv_b, fc_w, fc_b, vbuf, c0);

    const int gemm_grid = (N_NODES + 63) / 64;
    // --- layer 1 ---
    gemm128_kernel<<<gemm_grid, 256, 0, stream>>>(x, W1, bufA, N_NODES);
    agg_kernel<<<N_NODES / 8, 256, 0, stream>>>((const float4*)bufA, erec, offs, tot,
                                                dinv, (const float4*)b1, (float4*)bufB);
    // --- layer 2 ---
    gemm128_kernel<<<gemm_grid, 256, 0, stream>>>(bufB, W2, bufA, N_NODES);
    agg_kernel<<<N_NODES / 8, 256, 0, stream>>>((const float4*)bufA, erec, offs, tot,
                                                dinv, (const float4*)b2, (float4*)bufB);
    // --- fused temporal conv + fc ---
    convfc_kernel<<<N_NODES, 128, 0, stream>>>(bufB, vbuf, c0, out, N_NODES);
}

// Round 4
// 227.412 us; speedup vs baseline: 1.7284x; 1.1030x over previous
//
#include <hip/hip_runtime.h>
#include <hip/hip_bf16.h>

#define N_NODES 10000
#define N_EDGES 640000
#define CH 128
#define NB 128               // histogram/scatter blocks
#define EPB (N_EDGES / NB)   // 5000 edges per block
#define NCHUNK 40            // ceil(N_NODES/256) scan chunks

// ---------------------------------------------------------------------------
// Phase A: per-block LDS histograms — SINGLE pass, count + weighted degree
// simultaneously in 80 KB LDS. No global atomics.
__global__ __launch_bounds__(256) void hist_kernel(const int* __restrict__ ei,
                                                   const float* __restrict__ ew,
                                                   int* __restrict__ hist,
                                                   float* __restrict__ dhist) {
    __shared__ int h[N_NODES];                 // 40 KB
    __shared__ float hf[N_NODES];              // 40 KB
    int b = blockIdx.x, t = threadIdx.x;
    for (int i = t; i < N_NODES; i += 256) { h[i] = 0; hf[i] = 0.0f; }
    __syncthreads();
    int e0 = b * EPB;
    for (int i = t; i < EPB; i += 256) {
        int c = ei[N_EDGES + e0 + i];
        float w = ew[e0 + i];
        atomicAdd(&h[c], 1);                   // LDS atomics
        atomicAdd(&hf[c], w);
    }
    __syncthreads();
    for (int i = t; i < N_NODES; i += 256) {
        hist[b * N_NODES + i] = h[i];
        dhist[b * N_NODES + i] = hf[i];
    }
}

// ---------------------------------------------------------------------------
// Phase B: reduce histograms -> tot, dinv, per-chunk sums csum[40].
// Extra block (blockIdx == NCHUNK) does the conv+fc weight folding.
__global__ __launch_bounds__(256) void reduce_kernel(const int* __restrict__ hist,
        const float* __restrict__ dhist, int* __restrict__ tot,
        float* __restrict__ dinv, int* __restrict__ csum,
        const float* __restrict__ conv_w, const float* __restrict__ conv_b,
        const float* __restrict__ fc_w, const float* __restrict__ fc_b,
        float* __restrict__ vbuf, float* __restrict__ c0) {
    int blk = blockIdx.x, t = threadIdx.x;
    if (blk == NCHUNK) {                       // folded prep_convfc
        for (int i = t; i <= 384; i += 256) {
            if (i < 384) {
                float s = 0.0f;
                for (int o = 0; o < CH; ++o) s += fc_w[o] * conv_w[o * 384 + i];
                vbuf[i] = s;
            } else {
                float s = fc_b[0];
                for (int o = 0; o < CH; ++o) s += fc_w[o] * conv_b[o];
                *c0 = s;
            }
        }
        return;
    }
    int n = blk * 256 + t;
    int c = 0;
    if (n < N_NODES) {
        float d = 0.0f;
        #pragma unroll 4
        for (int b = 0; b < NB; ++b) {
            c += hist[b * N_NODES + n];
            d += dhist[b * N_NODES + n];
        }
        tot[n] = c;
        dinv[n] = rsqrtf(d + 1.0f);            // +1 = self-loop weight
    }
    // block-reduce c -> csum[blk]
    __shared__ int wred[4];
    int lane = t & 63, wave = t >> 6;
    int s = c;
    #pragma unroll
    for (int off = 32; off > 0; off >>= 1) s += __shfl_down(s, off, 64);
    if (lane == 0) wred[wave] = s;
    __syncthreads();
    if (t == 0) csum[blk] = wred[0] + wred[1] + wred[2] + wred[3];
}

// ---------------------------------------------------------------------------
// Phase C: offs[n] = global exclusive prefix of tot (chunk base from csum +
// local 256-wide shuffle scan), then convert hist columns into start cursors.
__global__ __launch_bounds__(256) void bofs_kernel(int* __restrict__ hist,
        const int* __restrict__ tot, const int* __restrict__ csum,
        int* __restrict__ offs) {
    __shared__ int lds_csum[NCHUNK];
    __shared__ int wsum[4];
    int blk = blockIdx.x, t = threadIdx.x;
    if (t < NCHUNK) lds_csum[t] = csum[t];
    __syncthreads();
    int base = 0;
    for (int i = 0; i < blk; ++i) base += lds_csum[i];
    int n = blk * 256 + t;
    int v = (n < N_NODES) ? tot[n] : 0;
    int lane = t & 63, wave = t >> 6;
    int s = v;                                  // inclusive wave scan
    #pragma unroll
    for (int off = 1; off < 64; off <<= 1) {
        int u = __shfl_up(s, off, 64);
        if (lane >= off) s += u;
    }
    if (lane == 63) wsum[wave] = s;
    __syncthreads();
    int wbase = 0;
    for (int i = 0; i < wave; ++i) wbase += wsum[i];
    if (n < N_NODES) {
        int run = base + wbase + s - v;         // global exclusive prefix
        offs[n] = run;
        for (int b = 0; b < NB; ++b) {
            int h = hist[b * N_NODES + n];
            hist[b * N_NODES + n] = run;
            run += h;
        }
    }
}

// ---------------------------------------------------------------------------
// Phase D: scatter edges into CSR order; packed {src, val} 8B records.
// dinv staged in LDS (40 KB) alongside the 40 KB cursor array.
__global__ __launch_bounds__(256) void scatter_kernel(const int* __restrict__ ei,
        const float* __restrict__ ew, const float* __restrict__ dinv,
        const int* __restrict__ bofs, int2* __restrict__ erec) {
    __shared__ int cur[N_NODES];               // 40 KB
    __shared__ float di[N_NODES];              // 40 KB
    int b = blockIdx.x, t = threadIdx.x;
    for (int i = t; i < N_NODES; i += 256) {
        cur[i] = bofs[b * N_NODES + i];
        di[i] = dinv[i];
    }
    __syncthreads();
    int e0 = b * EPB;
    for (int i = t; i < EPB; i += 256) {
        int e = e0 + i;
        int r = ei[e];
        int c = ei[N_EDGES + e];
        int p = atomicAdd(&cur[c], 1);         // LDS atomic
        float v = di[r] * ew[e] * di[c];
        erec[p] = make_int2(r, __float_as_int(v));
    }
}

// ---------------------------------------------------------------------------
// GEMM: out[m][o] = sum_k A[m][k] * W[o][k];  A:[M][128], W:[128][128] row-major.
__global__ __launch_bounds__(256) void gemm128_kernel(const float* __restrict__ A,
                                                      const float* __restrict__ W,
                                                      float* __restrict__ out, int M) {
    __shared__ float As[32][68];
    __shared__ float Ws[32][132];
    int tid = threadIdx.x;
    int tx = tid & 31;
    int ty = tid >> 5;
    int row0 = blockIdx.x * 64;
    float acc[8][4] = {};
    for (int k0 = 0; k0 < 128; k0 += 32) {
        #pragma unroll
        for (int i = 0; i < 8; ++i) {
            int idx = tid + i * 256;
            int r = idx >> 5, k = idx & 31;
            int gr = row0 + r;
            As[k][r] = (gr < M) ? A[gr * CH + k0 + k] : 0.0f;
        }
        #pragma unroll
        for (int i = 0; i < 16; ++i) {
            int idx = tid + i * 256;
            int o = idx >> 5, k = idx & 31;
            Ws[k][o] = W[o * CH + k0 + k];
        }
        __syncthreads();
        #pragma unroll
        for (int kk = 0; kk < 32; ++kk) {
            float a[8], w[4];
            #pragma unroll
            for (int j = 0; j < 8; ++j) a[j] = As[kk][ty * 8 + j];
            #pragma unroll
            for (int c = 0; c < 4; ++c) w[c] = Ws[kk][tx * 4 + c];
            #pragma unroll
            for (int j = 0; j < 8; ++j)
                #pragma unroll
                for (int c = 0; c < 4; ++c)
                    acc[j][c] += a[j] * w[c];
        }
        __syncthreads();
    }
    #pragma unroll
    for (int j = 0; j < 8; ++j) {
        int gr = row0 + ty * 8 + j;
        if (gr < M) {
            float4 v = make_float4(acc[j][0], acc[j][1], acc[j][2], acc[j][3]);
            *reinterpret_cast<float4*>(&out[gr * CH + tx * 4]) = v;
        }
    }
}

// ---------------------------------------------------------------------------
// Aggregation: 32 lanes per node (float4/lane), 8 nodes/block, unroll x8.
__global__ __launch_bounds__(256) void agg_kernel(const float4* __restrict__ xw4,
        const int2* __restrict__ erec, const int* __restrict__ offs,
        const int* __restrict__ cnt, const float* __restrict__ dinv,
        const float4* __restrict__ bias4, float4* __restrict__ out4) {
    int l = threadIdx.x & 31;                  // channel quad
    int g = threadIdx.x >> 5;                  // node group 0..7
    int n = blockIdx.x * 8 + g;
    float d = dinv[n];
    float dd = d * d;
    float4 self = xw4[n * 32 + l];
    float4 acc = make_float4(dd * self.x, dd * self.y, dd * self.z, dd * self.w);
    int start = offs[n];
    int num = cnt[n];
    int i = 0;
    for (; i + 8 <= num; i += 8) {
        int2 r[8];
        #pragma unroll
        for (int j = 0; j < 8; ++j) r[j] = erec[start + i + j];
        float4 f[8];
        #pragma unroll
        for (int j = 0; j < 8; ++j) f[j] = xw4[r[j].x * 32 + l];
        #pragma unroll
        for (int j = 0; j < 8; ++j) {
            float v = __int_as_float(r[j].y);
            acc.x += v * f[j].x; acc.y += v * f[j].y;
            acc.z += v * f[j].z; acc.w += v * f[j].w;
        }
    }
    for (; i < num; ++i) {
        int2 r = erec[start + i];
        float4 f = xw4[r.x * 32 + l];
        float v = __int_as_float(r.y);
        acc.x += v * f.x; acc.y += v * f.y; acc.z += v * f.z; acc.w += v * f.w;
    }
    float4 bb = bias4[l];
    acc.x = fmaxf(acc.x + bb.x, 0.0f);
    acc.y = fmaxf(acc.y + bb.y, 0.0f);
    acc.z = fmaxf(acc.z + bb.z, 0.0f);
    acc.w = fmaxf(acc.w + bb.w, 0.0f);
    out4[n * 32 + l] = acc;
}

// ---------------------------------------------------------------------------
__global__ __launch_bounds__(128) void convfc_kernel(const float* __restrict__ h,
        const float* __restrict__ v, const float* __restrict__ c0,
        float* __restrict__ out, int N) {
    int n = blockIdx.x;
    int t = threadIdx.x;
    float p = 0.0f;
    if (n > 0)     p += h[(n - 1) * CH + t] * v[t * 3 + 0];
    p += h[n * CH + t] * v[t * 3 + 1];
    if (n < N - 1) p += h[(n + 1) * CH + t] * v[t * 3 + 2];
    #pragma unroll
    for (int off = 32; off > 0; off >>= 1) p += __shfl_down(p, off, 64);
    __shared__ float red[2];
    if ((t & 63) == 0) red[t >> 6] = p;
    __syncthreads();
    if (t == 0) out[n] = red[0] + red[1] + *c0;
}

// ---------------------------------------------------------------------------
extern "C" void kernel_launch(void* const* d_in, const int* in_sizes, int n_in,
                              void* d_out, int out_size, void* d_ws, size_t ws_size,
                              hipStream_t stream) {
    const float* x       = (const float*)d_in[0];
    const int*   ei      = (const int*)d_in[1];
    const float* ew      = (const float*)d_in[2];
    const float* W1      = (const float*)d_in[3];
    const float* b1      = (const float*)d_in[4];
    const float* W2      = (const float*)d_in[5];
    const float* b2      = (const float*)d_in[6];
    const float* conv_w  = (const float*)d_in[7];
    const float* conv_b  = (const float*)d_in[8];
    const float* fc_w    = (const float*)d_in[9];
    const float* fc_b    = (const float*)d_in[10];
    float* out = (float*)d_out;

    // Workspace layout with stream-ordered aliasing:
    //   hist  (NB*10000 i) aliases bufA (hist dead after scatter; bufA first
    //                                    written by gemm1, later in stream)
    //   dhist (NB*10000 f) aliases erec (dhist dead after reduce; erec first
    //                                    written by scatter, later in stream)
    float* bufA   = (float*)d_ws;                   // 1,280,000 f
    float* bufB   = bufA + N_NODES * CH;            // 1,280,000 f
    int2*  erec   = (int2*)(bufB + N_NODES * CH);   // 640,000 x 8B
    int*   hist   = (int*)bufA;                     // alias
    float* dhist  = (float*)erec;                   // alias
    int*   tot    = (int*)(erec + N_EDGES);         // 10,000 i
    int*   offs   = tot + N_NODES;                  // 10,000 i
    float* dinv   = (float*)(offs + N_NODES);       // 10,000 f
    float* vbuf   = dinv + N_NODES;                 // 384 f
    float* c0     = vbuf + 384;                     // 1 f
    int*   csum   = (int*)(c0 + 1);                 // NCHUNK i

    // --- CSR build, atomic-free at global scope ---
    hist_kernel<<<NB, 256, 0, stream>>>(ei, ew, hist, dhist);
    reduce_kernel<<<NCHUNK + 1, 256, 0, stream>>>(hist, dhist, tot, dinv, csum,
                                                  conv_w, conv_b, fc_w, fc_b, vbuf, c0);
    bofs_kernel<<<NCHUNK, 256, 0, stream>>>(hist, tot, csum, offs);
    scatter_kernel<<<NB, 256, 0, stream>>>(ei, ew, dinv, hist, erec);

    const int gemm_grid = (N_NODES + 63) / 64;
    // --- layer 1 ---
    gemm128_kernel<<<gemm_grid, 256, 0, stream>>>(x, W1, bufA, N_NODES);
    agg_kernel<<<N_NODES / 8, 256, 0, stream>>>((const float4*)bufA, erec, offs, tot,
                                                dinv, (const float4*)b1, (float4*)bufB);
    // --- layer 2 ---
    gemm128_kernel<<<gemm_grid, 256, 0, stream>>>(bufB, W2, bufA, N_NODES);
    agg_kernel<<<N_NODES / 8, 256, 0, stream>>>((const float4*)bufA, erec, offs, tot,
                                                dinv, (const float4*)b2, (float4*)bufB);
    // --- fused temporal conv + fc ---
    convfc_kernel<<<N_NODES, 128, 0, stream>>>(bufB, vbuf, c0, out, N_NODES);
}